// Round 3
// baseline (1018.833 us; speedup 1.0000x reference)
//
#include <hip/hip_runtime.h>

typedef unsigned short u16;
typedef unsigned int u32;
typedef __attribute__((ext_vector_type(8))) __bf16 bf16x8;
typedef __attribute__((ext_vector_type(4))) float f32x4;

// ---------- helpers ----------
__device__ __forceinline__ void gl_lds16(const void* g, void* l) {
  // async global->LDS, 16B per lane; LDS dest = wave-uniform base + lane*16
  __builtin_amdgcn_global_load_lds((__attribute__((address_space(1))) void*)g,
                                   (__attribute__((address_space(3))) void*)l,
                                   16, 0, 0);
}

__device__ __forceinline__ u16 f2bf(float f) {
  // RNE float->bf16 (inputs are finite; NaN not handled)
  u32 x = __builtin_bit_cast(u32, f);
  return (u16)((x + 0x7fffu + ((x >> 16) & 1u)) >> 16);
}

// ---------- fused fp32 -> bf16 convert for all 7 tensors (1 launch) ----------
__global__ __launch_bounds__(256) void cvt_all(
    const float* __restrict__ q, const float* __restrict__ k, const float* __restrict__ v,
    const float* __restrict__ wq, const float* __restrict__ wk, const float* __restrict__ wv,
    const float* __restrict__ wo,
    u16* __restrict__ xq, u16* __restrict__ xk, u16* __restrict__ xv,
    u16* __restrict__ owq, u16* __restrict__ owk, u16* __restrict__ owv,
    u16* __restrict__ owo) {
  int bid = blockIdx.x;
  const float* src;
  u16* dst;
  int chunk;
  if (bid < 12288) {
    int t = bid >> 12;
    chunk = bid & 4095;
    src = (t == 0) ? q : (t == 1) ? k : v;
    dst = (t == 0) ? xq : (t == 1) ? xk : xv;
  } else {
    int b2 = bid - 12288;
    int t = b2 >> 11;
    chunk = b2 & 2047;
    src = (t == 0) ? wq : (t == 1) ? wk : (t == 2) ? wv : wo;
    dst = (t == 0) ? owq : (t == 1) ? owk : (t == 2) ? owv : owo;
  }
  int i = (chunk * 256 + (int)threadIdx.x) * 8;
  const float4* p = (const float4*)(src + i);
  float4 a = p[0], b = p[1];
  uint4 u;
  u.x = f2bf(a.x) | ((u32)f2bf(a.y) << 16);
  u.y = f2bf(a.z) | ((u32)f2bf(a.w) << 16);
  u.z = f2bf(b.x) | ((u32)f2bf(b.y) << 16);
  u.w = f2bf(b.z) | ((u32)f2bf(b.w) << 16);
  *(uint4*)(dst + i) = u;
}

// ---------- phase-pipelined C = A * B^T  (256x128 tile, BK=64, 8 waves) ----------
// Waves: 4(M) x 2(N); per-wave output 64x64 = 4x4 frags of 16x16, acc = 64 VGPR.
// LDS: double-buffered A[256x64] + B[128x64] bf16 = 96 KiB, 1 block/CU.
// Rows are 64 bf16 = 8 chunks of 16B; chunk slot = c ^ (row&7) -> ds_read_b128
// lands at the free 2-way conflict level. Staged via pre-swizzled global source
// + linear LDS dest (gl_lds requirement).
// Per K-tile: 4 phases, each = {ds_read quadrant ops; prefetch issue; s_barrier;
// setprio(1) 8xMFMA setprio(0)}; ONE vmcnt(0)+barrier per tile (prefetch issued
// 2-4 phases before the wait -> drain nearly free; raw barriers avoid the
// __syncthreads implicit vmcnt(0) that would kill in-flight prefetch).
template <bool F32OUT>
__device__ __forceinline__ void gemm8_body(const u16* __restrict__ A, const u16* __restrict__ B,
                                           void* __restrict__ Cptr, int m0, int n0, int N, int K,
                                           u16 (*As)[16384], u16 (*Bs)[8192]) {
  const int tid = threadIdx.x;
  const int lane = tid & 63, w = tid >> 6;
  const int wr = w >> 1, wc = w & 1;         // wave tile: rows wr*64, cols wc*64
  const int fm = lane & 15, quad = lane >> 4;
  const int sr = lane >> 3, sc = lane & 7;   // staging: row-in-issue, chunk slot
  f32x4 acc[4][4] = {};

// issue i covers 8 rows; this thread stages row i*8+sr, slot sc holds chunk sc^sr
#define STAGE_A8(buf, kt1, i) \
  gl_lds16(A + (size_t)(m0 + (i) * 8 + sr) * K + (kt1) * 64 + ((sc ^ sr) << 3), &As[buf][(i) * 512])
#define STAGE_B8(buf, kt1, i) \
  gl_lds16(B + (size_t)(n0 + (i) * 8 + sr) * K + (kt1) * 64 + ((sc ^ sr) << 3), &Bs[buf][(i) * 512])

  // prologue: stage K-tile 0 into buffer 0 (6 loads/thread)
  for (int i = w; i < 32; i += 8) STAGE_A8(0, 0, i);
  for (int i = w; i < 16; i += 8) STAGE_B8(0, 0, i);
  asm volatile("s_waitcnt vmcnt(0)" ::: "memory");
  __builtin_amdgcn_s_barrier();

  const int NKT = K >> 6;
  for (int kt = 0; kt < NKT; kt++) {
    const int cur = kt & 1, nxt = cur ^ 1;
    const bool pf = (kt + 1 < NKT);
    bf16x8 af[2][2][2], bf[2][2][2];  // [mq|nq][frag][ks]

    // ---- phase 0: quadrant (0,0); read A(mq0)+B(nq0); prefetch A of kt+1
#pragma unroll
    for (int f = 0; f < 2; f++)
#pragma unroll
      for (int ks = 0; ks < 2; ks++) {
        int ra = wr * 64 + f * 16 + fm;
        af[0][f][ks] = *(const bf16x8*)&As[cur][ra * 64 + (((ks * 4 + quad) ^ (ra & 7)) << 3)];
        int rb = wc * 64 + f * 16 + fm;
        bf[0][f][ks] = *(const bf16x8*)&Bs[cur][rb * 64 + (((ks * 4 + quad) ^ (rb & 7)) << 3)];
      }
    if (pf) {
      for (int i = w; i < 32; i += 8) STAGE_A8(nxt, kt + 1, i);
    }
    __builtin_amdgcn_s_barrier();
    __builtin_amdgcn_s_setprio(1);
#pragma unroll
    for (int mf = 0; mf < 2; mf++)
#pragma unroll
      for (int nf = 0; nf < 2; nf++)
#pragma unroll
        for (int ks = 0; ks < 2; ks++)
          acc[mf][nf] = __builtin_amdgcn_mfma_f32_16x16x32_bf16(af[0][mf][ks], bf[0][nf][ks], acc[mf][nf], 0, 0, 0);
    __builtin_amdgcn_s_setprio(0);

    // ---- phase 1: quadrant (1,0); read A(mq1); prefetch B of kt+1
#pragma unroll
    for (int f = 0; f < 2; f++)
#pragma unroll
      for (int ks = 0; ks < 2; ks++) {
        int ra = wr * 64 + 32 + f * 16 + fm;
        af[1][f][ks] = *(const bf16x8*)&As[cur][ra * 64 + (((ks * 4 + quad) ^ (ra & 7)) << 3)];
      }
    if (pf) {
      for (int i = w; i < 16; i += 8) STAGE_B8(nxt, kt + 1, i);
    }
    __builtin_amdgcn_s_barrier();
    __builtin_amdgcn_s_setprio(1);
#pragma unroll
    for (int mf = 0; mf < 2; mf++)
#pragma unroll
      for (int nf = 0; nf < 2; nf++)
#pragma unroll
        for (int ks = 0; ks < 2; ks++)
          acc[2 + mf][nf] = __builtin_amdgcn_mfma_f32_16x16x32_bf16(af[1][mf][ks], bf[0][nf][ks], acc[2 + mf][nf], 0, 0, 0);
    __builtin_amdgcn_s_setprio(0);

    // ---- phase 2: quadrant (0,1); read B(nq1)
#pragma unroll
    for (int f = 0; f < 2; f++)
#pragma unroll
      for (int ks = 0; ks < 2; ks++) {
        int rb = wc * 64 + 32 + f * 16 + fm;
        bf[1][f][ks] = *(const bf16x8*)&Bs[cur][rb * 64 + (((ks * 4 + quad) ^ (rb & 7)) << 3)];
      }
    __builtin_amdgcn_s_barrier();
    __builtin_amdgcn_s_setprio(1);
#pragma unroll
    for (int mf = 0; mf < 2; mf++)
#pragma unroll
      for (int nf = 0; nf < 2; nf++)
#pragma unroll
        for (int ks = 0; ks < 2; ks++)
          acc[mf][2 + nf] = __builtin_amdgcn_mfma_f32_16x16x32_bf16(af[0][mf][ks], bf[1][nf][ks], acc[mf][2 + nf], 0, 0, 0);
    __builtin_amdgcn_s_setprio(0);

    // ---- phase 3: quadrant (1,1); all-reuse, no reads
    __builtin_amdgcn_s_setprio(1);
#pragma unroll
    for (int mf = 0; mf < 2; mf++)
#pragma unroll
      for (int nf = 0; nf < 2; nf++)
#pragma unroll
        for (int ks = 0; ks < 2; ks++)
          acc[2 + mf][2 + nf] = __builtin_amdgcn_mfma_f32_16x16x32_bf16(af[1][mf][ks], bf[1][nf][ks], acc[2 + mf][2 + nf], 0, 0, 0);
    __builtin_amdgcn_s_setprio(0);

    // ---- K-tile boundary: drain this tile's prefetch (issued 2-4 phases ago)
    if (pf) asm volatile("s_waitcnt vmcnt(0)" ::: "memory");
    __builtin_amdgcn_s_barrier();
  }
#undef STAGE_A8
#undef STAGE_B8

  // epilogue: C write
#pragma unroll
  for (int fi = 0; fi < 4; fi++)
#pragma unroll
    for (int fj = 0; fj < 4; fj++)
#pragma unroll
      for (int r = 0; r < 4; r++) {
        size_t idx = (size_t)(m0 + wr * 64 + fi * 16 + quad * 4 + r) * N + (n0 + wc * 64 + fj * 16 + fm);
        if (F32OUT) ((float*)Cptr)[idx] = acc[fi][fj][r];
        else        ((u16*)Cptr)[idx] = f2bf(acc[fi][fj][r]);
      }
}

// Batched Q/K/V projection, 768 blocks (3 exact CU-rounds), XCD-chunked swizzle.
//  work z=0: Qb = Xq*Wq^T [4096x2048], z=1: Kb = Xk*Wk^T, z=2: Vt = Wv*Xv^T [2048x4096]
__global__ __launch_bounds__(512, 2)
void gemm_qkv8(const u16* __restrict__ Xq, const u16* __restrict__ Wqb, u16* __restrict__ Qb,
               const u16* __restrict__ Xk, const u16* __restrict__ Wkb, u16* __restrict__ Kb,
               const u16* __restrict__ Xv, const u16* __restrict__ Wvb, u16* __restrict__ Vt) {
  __shared__ u16 As[2][16384];
  __shared__ u16 Bs[2][8192];
  const int flat = blockIdx.x;                 // 768 = 8 XCD chunks of 96
  const int work = (flat & 7) * 96 + (flat >> 3);
  const int z = work >> 8, r = work & 255;
  const u16 *A, *B;
  u16* C;
  int N, m0, n0;
  if (z == 0) {
    A = Xq; B = Wqb; C = Qb; N = 2048;
    m0 = (r >> 4) << 8; n0 = (r & 15) << 7;    // 16 x 16 tiles of 256x128
  } else if (z == 1) {
    A = Xk; B = Wkb; C = Kb; N = 2048;
    m0 = (r >> 4) << 8; n0 = (r & 15) << 7;
  } else {
    A = Wvb; B = Xv; C = Vt; N = 4096;
    m0 = (r >> 5) << 8; n0 = (r & 31) << 7;    // 8 x 32 tiles
  }
  gemm8_body<false>(A, B, C, m0, n0, N, 2048, As, Bs);
}

// Output projection: out = ctx * Wo^T, fp32; 256 blocks (1 exact round)
__global__ __launch_bounds__(512, 2)
void gemm_out8(const u16* __restrict__ A, const u16* __restrict__ B, float* __restrict__ C) {
  __shared__ u16 As[2][16384];
  __shared__ u16 Bs[2][8192];
  const int flat = blockIdx.x;                 // 256 = 8 chunks of 32
  const int work = ((flat & 7) << 5) + (flat >> 3);
  const int m0 = (work >> 4) << 8, n0 = (work & 15) << 7;
  gemm8_body<true>(A, B, C, m0, n0, 2048, 2048, As, Bs);
}

// ---------- attention: per-64-key-block softmax, block outputs summed ----------
// 512 threads / 8 waves (16 q-rows each) -> 4 waves/SIMD; XCD-chunked block
// swizzle (each XCD owns 4 heads' K/V = one L2). Double-buffered K/V staging,
// single vmcnt(0)+s_barrier per iter, setprio around MFMA.
// Vt layout: [d 2048][b*2048+s] (row stride 4096).
__global__ __launch_bounds__(512, 4)
void attn_kernel(const u16* __restrict__ Q, const u16* __restrict__ Kmat,
                 const u16* __restrict__ Vt, float* __restrict__ attn_out,
                 u16* __restrict__ ctx) {
  __shared__ u16 Ks[2][64 * 128];   // [key][hd], 16B-chunk pos = c ^ (key&15)
  __shared__ u16 Vts[2][128 * 64];  // [dd][key], chunk pos = c ^ (dd&7)
  __shared__ u16 Ps[128 * 64];      // [qrow][key], chunk pos = c ^ (row&7); wave-private rows
  const int tid = threadIdx.x, lane = tid & 63, w = tid >> 6;  // w in 0..7
  const int flat = blockIdx.x + (blockIdx.y << 4) + (blockIdx.z << 8);
  const int work = ((flat & 7) << 6) + (flat >> 3);
  const int qt = work & 15, h = (work >> 4) & 15, b = work >> 8;
  const int q0 = qt * 128;
  const int fm = lane & 15, quad = lane >> 4;
  // (1/sqrt(128)) * log2(e): softmax exp((v-mx)/scale) == exp2((v-mx)*c)
  const float c_e2 = 0.088388347648318447f * 1.4426950408889634f;

  // Q fragments in registers: wave w owns q-rows [w*16, w*16+16)
  bf16x8 qf[4];
  {
    const u16* Qg = Q + (size_t)(b * 2048 + q0 + w * 16 + fm) * 2048 + h * 128;
#pragma unroll
    for (int kt = 0; kt < 4; kt++)
      qf[kt] = *(const bf16x8*)(Qg + kt * 32 + quad * 8);
  }
  f32x4 cacc[8] = {};  // ctx accumulator, persists across all 32 k-blocks
  const u16* Kg = Kmat + (size_t)b * 2048 * 2048 + h * 128;
  const u16* Vg = Vt + (size_t)(h * 128) * 4096 + b * 2048;
  const int krl = lane >> 4, kcl = lane & 15;  // K staging: 4 rows x 16 chunks / issue
  const int vrl = lane >> 3, vcl = lane & 7;   // V staging: 8 rows x 8 chunks / issue

#define STAGE(buf, kbb)                                                              \
  for (int i = w; i < 16; i += 8) {                                                  \
    int rk = i * 4 + krl;                                                            \
    int ck = kcl ^ (rk & 15);                                                        \
    gl_lds16(Kg + (size_t)((kbb) * 64 + rk) * 2048 + ck * 8, &Ks[(buf)][i * 512]);   \
    int rv = i * 8 + vrl;                                                            \
    int cv = vcl ^ (rv & 7);                                                         \
    gl_lds16(Vg + (size_t)rv * 4096 + (kbb) * 64 + cv * 8, &Vts[(buf)][i * 512]);    \
  }

  // prologue: stage k-block 0 into buffer 0
  STAGE(0, 0)
  asm volatile("s_waitcnt vmcnt(0)" ::: "memory");
  __builtin_amdgcn_s_barrier();

  for (int kb = 0; kb < 32; kb++) {
    const int cur = kb & 1;
    // issue next tile's async loads first; latency hides under compute below
    if (kb < 31) { STAGE(cur ^ 1, kb + 1) }

    // S = Q K^T  (this wave: 16 q-rows x 64 keys)
    f32x4 sacc[4] = {};
#pragma unroll
    for (int kt = 0; kt < 4; kt++) {
      bf16x8 kf[4];
#pragma unroll
      for (int nt = 0; nt < 4; nt++) {
        int rk = nt * 16 + fm;
        int ck = (kt * 4 + quad) ^ (rk & 15);
        kf[nt] = *(const bf16x8*)&Ks[cur][rk * 128 + ck * 8];
      }
      __builtin_amdgcn_s_setprio(1);
#pragma unroll
      for (int nt = 0; nt < 4; nt++)
        sacc[nt] = __builtin_amdgcn_mfma_f32_16x16x32_bf16(qf[kt], kf[nt], sacc[nt], 0, 0, 0);
      __builtin_amdgcn_s_setprio(0);
    }

    // per-row softmax over this 64-key block; write fp32 probs + bf16 P tile
#pragma unroll
    for (int r = 0; r < 4; r++) {
      float v0 = sacc[0][r], v1 = sacc[1][r], v2 = sacc[2][r], v3 = sacc[3][r];
      float mx = fmaxf(fmaxf(v0, v1), fmaxf(v2, v3));
      mx = fmaxf(mx, __shfl_xor(mx, 1));
      mx = fmaxf(mx, __shfl_xor(mx, 2));
      mx = fmaxf(mx, __shfl_xor(mx, 4));
      mx = fmaxf(mx, __shfl_xor(mx, 8));
      float e0 = exp2f((v0 - mx) * c_e2);
      float e1 = exp2f((v1 - mx) * c_e2);
      float e2 = exp2f((v2 - mx) * c_e2);
      float e3 = exp2f((v3 - mx) * c_e2);
      float s = e0 + e1 + e2 + e3;
      s += __shfl_xor(s, 1);
      s += __shfl_xor(s, 2);
      s += __shfl_xor(s, 4);
      s += __shfl_xor(s, 8);
      float inv = __builtin_amdgcn_rcpf(s);  // s in [1,64]; ~1ulp, well within tol
      float p0 = e0 * inv, p1 = e1 * inv, p2 = e2 * inv, p3 = e3 * inv;
      int row = w * 16 + quad * 4 + r;
      size_t ob = ((size_t)((b * 16 + h) * 2048 + q0 + row)) * 2048 + kb * 64;
      attn_out[ob + fm] = p0;
      attn_out[ob + 16 + fm] = p1;
      attn_out[ob + 32 + fm] = p2;
      attn_out[ob + 48 + fm] = p3;
      int rw7 = row & 7, fh = fm >> 3, fl = fm & 7;
      u16* pp = &Ps[row * 64];
      pp[(((0 + fh) ^ rw7) << 3) + fl] = f2bf(p0);
      pp[(((2 + fh) ^ rw7) << 3) + fl] = f2bf(p1);
      pp[(((4 + fh) ^ rw7) << 3) + fl] = f2bf(p2);
      pp[(((6 + fh) ^ rw7) << 3) + fl] = f2bf(p3);
    }

    // ctx += P * V   (Ps rows are wave-private: no barrier needed)
#pragma unroll
    for (int kt = 0; kt < 2; kt++) {
      bf16x8 pa, vb[8];
      {
        int rp = w * 16 + fm;
        int cp = (kt * 4 + quad) ^ (rp & 7);
        pa = *(const bf16x8*)&Ps[rp * 64 + cp * 8];
      }
#pragma unroll
      for (int nt = 0; nt < 8; nt++) {
        int rv = nt * 16 + fm;
        int cv = (kt * 4 + quad) ^ (rv & 7);
        vb[nt] = *(const bf16x8*)&Vts[cur][rv * 64 + cv * 8];
      }
      __builtin_amdgcn_s_setprio(1);
#pragma unroll
      for (int nt = 0; nt < 8; nt++)
        cacc[nt] = __builtin_amdgcn_mfma_f32_16x16x32_bf16(pa, vb[nt], cacc[nt], 0, 0, 0);
      __builtin_amdgcn_s_setprio(0);
    }

    // prefetch (issued at top of iter) has had the whole compute phase to land
    if (kb < 31) {
      asm volatile("s_waitcnt vmcnt(0)" ::: "memory");
      __builtin_amdgcn_s_barrier();
    }
  }
#undef STAGE

  // ctx [B,S,D] layout (= transpose(0,2,1,3).reshape fused)
#pragma unroll
  for (int nt = 0; nt < 8; nt++)
#pragma unroll
    for (int r = 0; r < 4; r++) {
      int row = q0 + w * 16 + quad * 4 + r;
      int col = h * 128 + nt * 16 + fm;
      ctx[(size_t)(b * 2048 + row) * 2048 + col] = f2bf(cacc[nt][r]);
    }
}

extern "C" void kernel_launch(void* const* d_in, const int* in_sizes, int n_in,
                              void* d_out, int out_size, void* d_ws, size_t ws_size,
                              hipStream_t stream) {
  const float* query = (const float*)d_in[0];
  const float* key   = (const float*)d_in[1];
  const float* value = (const float*)d_in[2];
  const float* Wq = (const float*)d_in[3];
  const float* Wk = (const float*)d_in[4];
  const float* Wv = (const float*)d_in[5];
  const float* Wo = (const float*)d_in[6];
  // d_in[7] = block_size (fixed 64)

  float* out  = (float*)d_out;
  float* attn = out + (size_t)8388608;  // [B,H,S,S] region

  // workspace (bf16, 96 MiB)
  u16* ws  = (u16*)d_ws;
  u16* wqb = ws;
  u16* wkb = wqb + 4194304;
  u16* wvb = wkb + 4194304;
  u16* wob = wvb + 4194304;
  u16* Qb  = wob + 4194304;
  u16* Kb  = Qb + 8388608;
  u16* Vtb = Kb + 8388608;   // [d 2048][b*s 4096] = V^T, written directly by gemm_qkv8
  u16* ctx = Vtb + 8388608;
  // bf16 input copies live in the attn-weights region (dead before attn writes it)
  u16* Xq = (u16*)attn;
  u16* Xk = Xq + 8388608;
  u16* Xv = Xk + 8388608;

  cvt_all<<<20480, 256, 0, stream>>>(query, key, value, Wq, Wk, Wv, Wo,
                                     Xq, Xk, Xv, wqb, wkb, wvb, wob);

  gemm_qkv8<<<768, 512, 0, stream>>>(Xq, wqb, Qb, Xk, wkb, Kb, Xv, wvb, Vtb);

  attn_kernel<<<dim3(16, 16, 2), 512, 0, stream>>>(Qb, Kb, Vtb, attn, ctx);

  gemm_out8<<<256, 512, 0, stream>>>(ctx, wob, out);
}

// Round 4
// 1015.060 us; speedup vs baseline: 1.0037x; 1.0037x over previous
//
#include <hip/hip_runtime.h>

typedef unsigned short u16;
typedef unsigned int u32;
typedef __attribute__((ext_vector_type(8))) __bf16 bf16x8;
typedef __attribute__((ext_vector_type(4))) float f32x4;

// ---------- helpers ----------
__device__ __forceinline__ void gl_lds16(const void* g, void* l) {
  // async global->LDS, 16B per lane; LDS dest = wave-uniform base + lane*16
  __builtin_amdgcn_global_load_lds((__attribute__((address_space(1))) void*)g,
                                   (__attribute__((address_space(3))) void*)l,
                                   16, 0, 0);
}

__device__ __forceinline__ u16 f2bf(float f) {
  // RNE float->bf16 (inputs are finite; NaN not handled)
  u32 x = __builtin_bit_cast(u32, f);
  return (u16)((x + 0x7fffu + ((x >> 16) & 1u)) >> 16);
}

// ---------- fused fp32 -> bf16 convert for all 7 tensors (1 launch) ----------
__global__ __launch_bounds__(256) void cvt_all(
    const float* __restrict__ q, const float* __restrict__ k, const float* __restrict__ v,
    const float* __restrict__ wq, const float* __restrict__ wk, const float* __restrict__ wv,
    const float* __restrict__ wo,
    u16* __restrict__ xq, u16* __restrict__ xk, u16* __restrict__ xv,
    u16* __restrict__ owq, u16* __restrict__ owk, u16* __restrict__ owv,
    u16* __restrict__ owo) {
  int bid = blockIdx.x;
  const float* src;
  u16* dst;
  int chunk;
  if (bid < 12288) {
    int t = bid >> 12;
    chunk = bid & 4095;
    src = (t == 0) ? q : (t == 1) ? k : v;
    dst = (t == 0) ? xq : (t == 1) ? xk : xv;
  } else {
    int b2 = bid - 12288;
    int t = b2 >> 11;
    chunk = b2 & 2047;
    src = (t == 0) ? wq : (t == 1) ? wk : (t == 2) ? wv : wo;
    dst = (t == 0) ? owq : (t == 1) ? owk : (t == 2) ? owv : owo;
  }
  int i = (chunk * 256 + (int)threadIdx.x) * 8;
  const float4* p = (const float4*)(src + i);
  float4 a = p[0], b = p[1];
  uint4 u;
  u.x = f2bf(a.x) | ((u32)f2bf(a.y) << 16);
  u.y = f2bf(a.z) | ((u32)f2bf(a.w) << 16);
  u.z = f2bf(b.x) | ((u32)f2bf(b.y) << 16);
  u.w = f2bf(b.z) | ((u32)f2bf(b.w) << 16);
  *(uint4*)(dst + i) = u;
}

// ---------- phase-pipelined C = A * B^T  (256x128 tile, BK=64, 8 waves) ----------
// Waves: 4(M) x 2(N); per-wave output 64x64 = 4x4 frags of 16x16, acc = 64 VGPR.
// v2 (T4 fix): TRIPLE-buffered LDS (A 3x32K + B 3x16K = 144 KiB) with COUNTED
// vmcnt at tile boundaries: during tile kt, phases 0/1 issue tile kt+2's 6
// loads/thread; boundary waits vmcnt(6) = drains only tile kt+1's loads (issued
// a full tile ago) while kt+2's stay in flight across the barrier. Never drains
// to 0 in steady state (m218: counted-vs-drain0 is the whole gain).
// Buffer safety: buf written during kt = buf read by kt-1; all its reads
// completed before the kt-1 -> kt boundary barrier.
// Rows are 64 bf16 = 8 chunks of 16B; chunk slot = c ^ (row&7) -> ds_read_b128
// at the free 2-way conflict level (pre-swizzled global src, linear LDS dest).
template <bool F32OUT>
__device__ __forceinline__ void gemm8_body(const u16* __restrict__ A, const u16* __restrict__ B,
                                           void* __restrict__ Cptr, int m0, int n0, int N, int K,
                                           u16 (*As)[16384], u16 (*Bs)[8192]) {
  const int tid = threadIdx.x;
  const int lane = tid & 63, w = tid >> 6;
  const int wr = w >> 1, wc = w & 1;         // wave tile: rows wr*64, cols wc*64
  const int fm = lane & 15, quad = lane >> 4;
  const int sr = lane >> 3, sc = lane & 7;   // staging: row-in-issue, chunk slot
  f32x4 acc[4][4] = {};

// issue i covers 8 rows; this thread stages row i*8+sr, slot sc holds chunk sc^sr
#define STAGE_A8(buf, kt1, i) \
  gl_lds16(A + (size_t)(m0 + (i) * 8 + sr) * K + (kt1) * 64 + ((sc ^ sr) << 3), &As[buf][(i) * 512])
#define STAGE_B8(buf, kt1, i) \
  gl_lds16(B + (size_t)(n0 + (i) * 8 + sr) * K + (kt1) * 64 + ((sc ^ sr) << 3), &Bs[buf][(i) * 512])

  // prologue: stage K-tiles 0 and 1 into buffers 0 and 1 (6 loads/thread each)
  for (int i = w; i < 32; i += 8) STAGE_A8(0, 0, i);
  for (int i = w; i < 16; i += 8) STAGE_B8(0, 0, i);
  for (int i = w; i < 32; i += 8) STAGE_A8(1, 1, i);
  for (int i = w; i < 16; i += 8) STAGE_B8(1, 1, i);
  asm volatile("s_waitcnt vmcnt(6)" ::: "memory");  // tile 0 landed; tile 1 in flight
  __builtin_amdgcn_s_barrier();

  const int NKT = K >> 6;
  int cur = 0;
  for (int kt = 0; kt < NKT; kt++) {
    int pfb = cur + 2; if (pfb >= 3) pfb -= 3;     // prefetch buffer = (kt+2)%3
    const bool pf = (kt + 2 < NKT);
    bf16x8 af[2][2][2], bf[2][2][2];  // [mq|nq][frag][ks]

    // ---- phase 0: quadrant (0,0); read A(mq0)+B(nq0); issue A-prefetch of kt+2
#pragma unroll
    for (int f = 0; f < 2; f++)
#pragma unroll
      for (int ks = 0; ks < 2; ks++) {
        int ra = wr * 64 + f * 16 + fm;
        af[0][f][ks] = *(const bf16x8*)&As[cur][ra * 64 + (((ks * 4 + quad) ^ (ra & 7)) << 3)];
        int rb = wc * 64 + f * 16 + fm;
        bf[0][f][ks] = *(const bf16x8*)&Bs[cur][rb * 64 + (((ks * 4 + quad) ^ (rb & 7)) << 3)];
      }
    if (pf) {
      for (int i = w; i < 32; i += 8) STAGE_A8(pfb, kt + 2, i);
    }
    __builtin_amdgcn_s_barrier();
    __builtin_amdgcn_s_setprio(1);
#pragma unroll
    for (int mf = 0; mf < 2; mf++)
#pragma unroll
      for (int nf = 0; nf < 2; nf++)
#pragma unroll
        for (int ks = 0; ks < 2; ks++)
          acc[mf][nf] = __builtin_amdgcn_mfma_f32_16x16x32_bf16(af[0][mf][ks], bf[0][nf][ks], acc[mf][nf], 0, 0, 0);
    __builtin_amdgcn_s_setprio(0);

    // ---- phase 1: quadrant (1,0); read A(mq1); issue B-prefetch of kt+2
#pragma unroll
    for (int f = 0; f < 2; f++)
#pragma unroll
      for (int ks = 0; ks < 2; ks++) {
        int ra = wr * 64 + 32 + f * 16 + fm;
        af[1][f][ks] = *(const bf16x8*)&As[cur][ra * 64 + (((ks * 4 + quad) ^ (ra & 7)) << 3)];
      }
    if (pf) {
      for (int i = w; i < 16; i += 8) STAGE_B8(pfb, kt + 2, i);
    }
    __builtin_amdgcn_s_barrier();
    __builtin_amdgcn_s_setprio(1);
#pragma unroll
    for (int mf = 0; mf < 2; mf++)
#pragma unroll
      for (int nf = 0; nf < 2; nf++)
#pragma unroll
        for (int ks = 0; ks < 2; ks++)
          acc[2 + mf][nf] = __builtin_amdgcn_mfma_f32_16x16x32_bf16(af[1][mf][ks], bf[0][nf][ks], acc[2 + mf][nf], 0, 0, 0);
    __builtin_amdgcn_s_setprio(0);

    // ---- phase 2: quadrant (0,1); read B(nq1)
#pragma unroll
    for (int f = 0; f < 2; f++)
#pragma unroll
      for (int ks = 0; ks < 2; ks++) {
        int rb = wc * 64 + 32 + f * 16 + fm;
        bf[1][f][ks] = *(const bf16x8*)&Bs[cur][rb * 64 + (((ks * 4 + quad) ^ (rb & 7)) << 3)];
      }
    __builtin_amdgcn_s_barrier();
    __builtin_amdgcn_s_setprio(1);
#pragma unroll
    for (int mf = 0; mf < 2; mf++)
#pragma unroll
      for (int nf = 0; nf < 2; nf++)
#pragma unroll
        for (int ks = 0; ks < 2; ks++)
          acc[mf][2 + nf] = __builtin_amdgcn_mfma_f32_16x16x32_bf16(af[0][mf][ks], bf[1][nf][ks], acc[mf][2 + nf], 0, 0, 0);
    __builtin_amdgcn_s_setprio(0);

    // ---- phase 3: quadrant (1,1); all-reuse, no reads
    __builtin_amdgcn_s_setprio(1);
#pragma unroll
    for (int mf = 0; mf < 2; mf++)
#pragma unroll
      for (int nf = 0; nf < 2; nf++)
#pragma unroll
        for (int ks = 0; ks < 2; ks++)
          acc[2 + mf][2 + nf] = __builtin_amdgcn_mfma_f32_16x16x32_bf16(af[1][mf][ks], bf[1][nf][ks], acc[2 + mf][2 + nf], 0, 0, 0);
    __builtin_amdgcn_s_setprio(0);

    // ---- K-tile boundary: counted wait (drain only tile kt+1's loads)
    if (kt + 1 < NKT) {
      if (pf) asm volatile("s_waitcnt vmcnt(6)" ::: "memory");
      else    asm volatile("s_waitcnt vmcnt(0)" ::: "memory");
      __builtin_amdgcn_s_barrier();
    }
    cur = cur + 1; if (cur >= 3) cur -= 3;
  }
#undef STAGE_A8
#undef STAGE_B8

  // epilogue: C write
#pragma unroll
  for (int fi = 0; fi < 4; fi++)
#pragma unroll
    for (int fj = 0; fj < 4; fj++)
#pragma unroll
      for (int r = 0; r < 4; r++) {
        size_t idx = (size_t)(m0 + wr * 64 + fi * 16 + quad * 4 + r) * N + (n0 + wc * 64 + fj * 16 + fm);
        if (F32OUT) ((float*)Cptr)[idx] = acc[fi][fj][r];
        else        ((u16*)Cptr)[idx] = f2bf(acc[fi][fj][r]);
      }
}

// Batched Q/K/V projection, 768 blocks (3 exact CU-rounds), XCD-chunked swizzle.
//  work z=0: Qb = Xq*Wq^T [4096x2048], z=1: Kb = Xk*Wk^T, z=2: Vt = Wv*Xv^T [2048x4096]
__global__ __launch_bounds__(512, 2)
void gemm_qkv8(const u16* __restrict__ Xq, const u16* __restrict__ Wqb, u16* __restrict__ Qb,
               const u16* __restrict__ Xk, const u16* __restrict__ Wkb, u16* __restrict__ Kb,
               const u16* __restrict__ Xv, const u16* __restrict__ Wvb, u16* __restrict__ Vt) {
  __shared__ u16 As[3][16384];
  __shared__ u16 Bs[3][8192];
  const int flat = blockIdx.x;                 // 768 = 8 XCD chunks of 96
  const int work = (flat & 7) * 96 + (flat >> 3);
  const int z = work >> 8, r = work & 255;
  const u16 *A, *B;
  u16* C;
  int N, m0, n0;
  if (z == 0) {
    A = Xq; B = Wqb; C = Qb; N = 2048;
    m0 = (r >> 4) << 8; n0 = (r & 15) << 7;    // 16 x 16 tiles of 256x128
  } else if (z == 1) {
    A = Xk; B = Wkb; C = Kb; N = 2048;
    m0 = (r >> 4) << 8; n0 = (r & 15) << 7;
  } else {
    A = Wvb; B = Xv; C = Vt; N = 4096;
    m0 = (r >> 5) << 8; n0 = (r & 31) << 7;    // 8 x 32 tiles
  }
  gemm8_body<false>(A, B, C, m0, n0, N, 2048, As, Bs);
}

// Output projection: out = ctx * Wo^T, fp32; 256 blocks (1 exact round)
__global__ __launch_bounds__(512, 2)
void gemm_out8(const u16* __restrict__ A, const u16* __restrict__ B, float* __restrict__ C) {
  __shared__ u16 As[3][16384];
  __shared__ u16 Bs[3][8192];
  const int flat = blockIdx.x;                 // 256 = 8 chunks of 32
  const int work = ((flat & 7) << 5) + (flat >> 3);
  const int m0 = (work >> 4) << 8, n0 = (work & 15) << 7;
  gemm8_body<true>(A, B, C, m0, n0, 2048, 2048, As, Bs);
}

// ---------- attention: per-64-key-block softmax, block outputs summed ----------
// 512 threads / 8 waves (16 q-rows each) -> 4 waves/SIMD; XCD-chunked block
// swizzle (each XCD owns 4 heads' K/V = one L2). Double-buffered K/V staging,
// single vmcnt(0)+s_barrier per iter, setprio around MFMA.
// Vt layout: [d 2048][b*2048+s] (row stride 4096).
__global__ __launch_bounds__(512, 4)
void attn_kernel(const u16* __restrict__ Q, const u16* __restrict__ Kmat,
                 const u16* __restrict__ Vt, float* __restrict__ attn_out,
                 u16* __restrict__ ctx) {
  __shared__ u16 Ks[2][64 * 128];   // [key][hd], 16B-chunk pos = c ^ (key&15)
  __shared__ u16 Vts[2][128 * 64];  // [dd][key], chunk pos = c ^ (dd&7)
  __shared__ u16 Ps[128 * 64];      // [qrow][key], chunk pos = c ^ (row&7); wave-private rows
  const int tid = threadIdx.x, lane = tid & 63, w = tid >> 6;  // w in 0..7
  const int flat = blockIdx.x + (blockIdx.y << 4) + (blockIdx.z << 8);
  const int work = ((flat & 7) << 6) + (flat >> 3);
  const int qt = work & 15, h = (work >> 4) & 15, b = work >> 8;
  const int q0 = qt * 128;
  const int fm = lane & 15, quad = lane >> 4;
  // (1/sqrt(128)) * log2(e): softmax exp((v-mx)/scale) == exp2((v-mx)*c)
  const float c_e2 = 0.088388347648318447f * 1.4426950408889634f;

  // Q fragments in registers: wave w owns q-rows [w*16, w*16+16)
  bf16x8 qf[4];
  {
    const u16* Qg = Q + (size_t)(b * 2048 + q0 + w * 16 + fm) * 2048 + h * 128;
#pragma unroll
    for (int kt = 0; kt < 4; kt++)
      qf[kt] = *(const bf16x8*)(Qg + kt * 32 + quad * 8);
  }
  f32x4 cacc[8] = {};  // ctx accumulator, persists across all 32 k-blocks
  const u16* Kg = Kmat + (size_t)b * 2048 * 2048 + h * 128;
  const u16* Vg = Vt + (size_t)(h * 128) * 4096 + b * 2048;
  const int krl = lane >> 4, kcl = lane & 15;  // K staging: 4 rows x 16 chunks / issue
  const int vrl = lane >> 3, vcl = lane & 7;   // V staging: 8 rows x 8 chunks / issue

#define STAGE(buf, kbb)                                                              \
  for (int i = w; i < 16; i += 8) {                                                  \
    int rk = i * 4 + krl;                                                            \
    int ck = kcl ^ (rk & 15);                                                        \
    gl_lds16(Kg + (size_t)((kbb) * 64 + rk) * 2048 + ck * 8, &Ks[(buf)][i * 512]);   \
    int rv = i * 8 + vrl;                                                            \
    int cv = vcl ^ (rv & 7);                                                         \
    gl_lds16(Vg + (size_t)rv * 4096 + (kbb) * 64 + cv * 8, &Vts[(buf)][i * 512]);    \
  }

  // prologue: stage k-block 0 into buffer 0
  STAGE(0, 0)
  asm volatile("s_waitcnt vmcnt(0)" ::: "memory");
  __builtin_amdgcn_s_barrier();

  for (int kb = 0; kb < 32; kb++) {
    const int cur = kb & 1;
    // issue next tile's async loads first; latency hides under compute below
    if (kb < 31) { STAGE(cur ^ 1, kb + 1) }

    // S = Q K^T  (this wave: 16 q-rows x 64 keys)
    f32x4 sacc[4] = {};
#pragma unroll
    for (int kt = 0; kt < 4; kt++) {
      bf16x8 kf[4];
#pragma unroll
      for (int nt = 0; nt < 4; nt++) {
        int rk = nt * 16 + fm;
        int ck = (kt * 4 + quad) ^ (rk & 15);
        kf[nt] = *(const bf16x8*)&Ks[cur][rk * 128 + ck * 8];
      }
      __builtin_amdgcn_s_setprio(1);
#pragma unroll
      for (int nt = 0; nt < 4; nt++)
        sacc[nt] = __builtin_amdgcn_mfma_f32_16x16x32_bf16(qf[kt], kf[nt], sacc[nt], 0, 0, 0);
      __builtin_amdgcn_s_setprio(0);
    }

    // per-row softmax over this 64-key block; write fp32 probs + bf16 P tile
#pragma unroll
    for (int r = 0; r < 4; r++) {
      float v0 = sacc[0][r], v1 = sacc[1][r], v2 = sacc[2][r], v3 = sacc[3][r];
      float mx = fmaxf(fmaxf(v0, v1), fmaxf(v2, v3));
      mx = fmaxf(mx, __shfl_xor(mx, 1));
      mx = fmaxf(mx, __shfl_xor(mx, 2));
      mx = fmaxf(mx, __shfl_xor(mx, 4));
      mx = fmaxf(mx, __shfl_xor(mx, 8));
      float e0 = exp2f((v0 - mx) * c_e2);
      float e1 = exp2f((v1 - mx) * c_e2);
      float e2 = exp2f((v2 - mx) * c_e2);
      float e3 = exp2f((v3 - mx) * c_e2);
      float s = e0 + e1 + e2 + e3;
      s += __shfl_xor(s, 1);
      s += __shfl_xor(s, 2);
      s += __shfl_xor(s, 4);
      s += __shfl_xor(s, 8);
      float inv = __builtin_amdgcn_rcpf(s);  // s in [1,64]; ~1ulp, well within tol
      float p0 = e0 * inv, p1 = e1 * inv, p2 = e2 * inv, p3 = e3 * inv;
      int row = w * 16 + quad * 4 + r;
      size_t ob = ((size_t)((b * 16 + h) * 2048 + q0 + row)) * 2048 + kb * 64;
      attn_out[ob + fm] = p0;
      attn_out[ob + 16 + fm] = p1;
      attn_out[ob + 32 + fm] = p2;
      attn_out[ob + 48 + fm] = p3;
      int rw7 = row & 7, fh = fm >> 3, fl = fm & 7;
      u16* pp = &Ps[row * 64];
      pp[(((0 + fh) ^ rw7) << 3) + fl] = f2bf(p0);
      pp[(((2 + fh) ^ rw7) << 3) + fl] = f2bf(p1);
      pp[(((4 + fh) ^ rw7) << 3) + fl] = f2bf(p2);
      pp[(((6 + fh) ^ rw7) << 3) + fl] = f2bf(p3);
    }

    // ctx += P * V   (Ps rows are wave-private: no barrier needed)
#pragma unroll
    for (int kt = 0; kt < 2; kt++) {
      bf16x8 pa, vb[8];
      {
        int rp = w * 16 + fm;
        int cp = (kt * 4 + quad) ^ (rp & 7);
        pa = *(const bf16x8*)&Ps[rp * 64 + cp * 8];
      }
#pragma unroll
      for (int nt = 0; nt < 8; nt++) {
        int rv = nt * 16 + fm;
        int cv = (kt * 4 + quad) ^ (rv & 7);
        vb[nt] = *(const bf16x8*)&Vts[cur][rv * 64 + cv * 8];
      }
      __builtin_amdgcn_s_setprio(1);
#pragma unroll
      for (int nt = 0; nt < 8; nt++)
        cacc[nt] = __builtin_amdgcn_mfma_f32_16x16x32_bf16(pa, vb[nt], cacc[nt], 0, 0, 0);
      __builtin_amdgcn_s_setprio(0);
    }

    // prefetch (issued at top of iter) has had the whole compute phase to land
    if (kb < 31) {
      asm volatile("s_waitcnt vmcnt(0)" ::: "memory");
      __builtin_amdgcn_s_barrier();
    }
  }
#undef STAGE

  // ctx [B,S,D] layout (= transpose(0,2,1,3).reshape fused)
#pragma unroll
  for (int nt = 0; nt < 8; nt++)
#pragma unroll
    for (int r = 0; r < 4; r++) {
      int row = q0 + w * 16 + quad * 4 + r;
      int col = h * 128 + nt * 16 + fm;
      ctx[(size_t)(b * 2048 + row) * 2048 + col] = f2bf(cacc[nt][r]);
    }
}

extern "C" void kernel_launch(void* const* d_in, const int* in_sizes, int n_in,
                              void* d_out, int out_size, void* d_ws, size_t ws_size,
                              hipStream_t stream) {
  const float* query = (const float*)d_in[0];
  const float* key   = (const float*)d_in[1];
  const float* value = (const float*)d_in[2];
  const float* Wq = (const float*)d_in[3];
  const float* Wk = (const float*)d_in[4];
  const float* Wv = (const float*)d_in[5];
  const float* Wo = (const float*)d_in[6];
  // d_in[7] = block_size (fixed 64)

  float* out  = (float*)d_out;
  float* attn = out + (size_t)8388608;  // [B,H,S,S] region

  // workspace (bf16, 96 MiB)
  u16* ws  = (u16*)d_ws;
  u16* wqb = ws;
  u16* wkb = wqb + 4194304;
  u16* wvb = wkb + 4194304;
  u16* wob = wvb + 4194304;
  u16* Qb  = wob + 4194304;
  u16* Kb  = Qb + 8388608;
  u16* Vtb = Kb + 8388608;   // [d 2048][b*s 4096] = V^T, written directly by gemm_qkv8
  u16* ctx = Vtb + 8388608;
  // bf16 input copies live in the attn-weights region (dead before attn writes it)
  u16* Xq = (u16*)attn;
  u16* Xk = Xq + 8388608;
  u16* Xv = Xk + 8388608;

  cvt_all<<<20480, 256, 0, stream>>>(query, key, value, Wq, Wk, Wv, Wo,
                                     Xq, Xk, Xv, wqb, wkb, wvb, wob);

  gemm_qkv8<<<768, 512, 0, stream>>>(Xq, wqb, Qb, Xk, wkb, Kb, Xv, wvb, Vtb);

  attn_kernel<<<dim3(16, 16, 2), 512, 0, stream>>>(Qb, Kb, Vtb, attn, ctx);

  gemm_out8<<<256, 512, 0, stream>>>(ctx, wob, out);
}